// Round 5
// baseline (1422.283 us; speedup 1.0000x reference)
//
#include <hip/hip_runtime.h>
#include <hip/hip_cooperative_groups.h>
#include <math.h>

namespace cg = cooperative_groups;

// Problem geometry (fixed by the reference)
#define BB 8
#define CC 256
#define HWSZ 36864            // floats per (b,c) slice
#define QF 9216               // floats per quarter slice
#define Q4 2304               // float4 per quarter slice
#define IT 9                  // float4 per thread per batch (9*256 = 2304)
#define INTERNAL 16
#define NBLK 1024             // 4 blocks/CU co-resident (LDS-limited: 4*37KB <= 160KB)
#define TPB 256

// ---------------- fused single-read cooperative kernel (LDS-staged) -------
// Block owns channel c = blk>>2, quarter q = blk&3. Per batch:
//   A: global -> LDS (36 KB) + sumsq partial -> pbuf[b][blk]
//   grid.sync()
//   B: gate MLP from 1024 partials (redundant per block; ~4k FLOP),
//      then LDS -> scale -> out.
// Inputs are read from HBM exactly once. Nothing big lives in VGPRs
// across the grid sync (R4's spill trap).
__global__ __launch_bounds__(TPB, 4) void se_fused_lds_kernel(
    const float* __restrict__ in, float* __restrict__ out,
    float* __restrict__ pbuf,          // [BB][NBLK]
    const float* __restrict__ w_down,  // [16, 256]
    const float* __restrict__ b_down,  // [16]
    const float* __restrict__ w_up,    // [256, 16]
    const float* __restrict__ b_up)    // [256]
{
    cg::grid_group grid = cg::this_grid();
    const int blk = blockIdx.x;
    const int c   = blk >> 2;
    const int q   = blk & 3;
    const int tid = threadIdx.x;
    const int lane = tid & 63, wave = tid >> 6;

    __shared__ float4 buf[Q4];         // 36 KB staging
    __shared__ float xs[CC];
    __shared__ float hs[INTERNAL];
    __shared__ float red[4];
    __shared__ float gsh;

    for (int b = 0; b < BB; ++b) {
        // ---- phase A: stage quarter-slice into LDS + sum of squares ----
        const float4* p = reinterpret_cast<const float4*>(
            in + ((size_t)(b * CC + c) * HWSZ) + (size_t)q * QF);
        float acc = 0.f;
        #pragma unroll
        for (int i = 0; i < IT; ++i) {
            float4 v = p[tid + i * TPB];
            buf[tid + i * TPB] = v;
            acc += v.x * v.x + v.y * v.y + v.z * v.z + v.w * v.w;
        }
        for (int off = 32; off > 0; off >>= 1)
            acc += __shfl_down(acc, off, 64);
        if (lane == 0) red[wave] = acc;
        __syncthreads();
        if (tid == 0) {
            pbuf[(size_t)b * NBLK + blk] = red[0] + red[1] + red[2] + red[3];
            __threadfence();           // make partial visible device-wide
        }
        grid.sync();

        // ---- phase B: gate MLP (channel tid's 4 partials are contiguous) --
        {
            float4 pp = reinterpret_cast<const float4*>(
                pbuf + (size_t)b * NBLK)[tid];
            float g = sqrtf(pp.x + pp.y + pp.z + pp.w);
            xs[tid] = g / (g + 1e-6f);
        }
        __syncthreads();
        {
            const int j = tid >> 4, l = tid & 15;   // 16 threads per hidden j
            const float* wr = w_down + j * CC;
            float a = 0.f;
            #pragma unroll
            for (int k = 0; k < CC / 16; ++k)
                a += xs[l + k * 16] * wr[l + k * 16];
            a += __shfl_down(a, 8, 16);
            a += __shfl_down(a, 4, 16);
            a += __shfl_down(a, 2, 16);
            a += __shfl_down(a, 1, 16);
            if (l == 0) hs[j] = fmaxf(a + b_down[j], 0.f);
        }
        __syncthreads();
        if (tid == 0) {
            float a = b_up[c];
            const float* wu = w_up + c * INTERNAL;
            #pragma unroll
            for (int j = 0; j < INTERNAL; ++j) a += hs[j] * wu[j];
            gsh = 1.f / (1.f + expf(-a));
        }
        __syncthreads();

        // ---- scale LDS-resident data and store ----
        const float gv = gsh;
        float4* po = reinterpret_cast<float4*>(
            out + ((size_t)(b * CC + c) * HWSZ) + (size_t)q * QF);
        #pragma unroll
        for (int i = 0; i < IT; ++i) {
            float4 w = buf[tid + i * TPB];
            w.x *= gv; w.y *= gv; w.z *= gv; w.w *= gv;
            po[tid + i * TPB] = w;
        }
        __syncthreads();               // buf reused by next batch's phase A
    }
}

// ---------------- fallback path (proven R1 kernels, 190 us) ----------------
#define HW4 (HWSZ / 4)

__global__ __launch_bounds__(256) void se_sumsq_kernel(
    const float* __restrict__ in, float* __restrict__ sumsq)
{
    const int bc = blockIdx.x;
    const float4* p = reinterpret_cast<const float4*>(in + (size_t)bc * HWSZ);
    float acc = 0.f;
    #pragma unroll 4
    for (int i = threadIdx.x; i < HW4; i += 256) {
        float4 v = p[i];
        acc += v.x * v.x + v.y * v.y + v.z * v.z + v.w * v.w;
    }
    for (int off = 32; off > 0; off >>= 1)
        acc += __shfl_down(acc, off, 64);
    __shared__ float lds[4];
    const int lane = threadIdx.x & 63, wave = threadIdx.x >> 6;
    if (lane == 0) lds[wave] = acc;
    __syncthreads();
    if (threadIdx.x == 0)
        sumsq[bc] = lds[0] + lds[1] + lds[2] + lds[3];
}

__global__ __launch_bounds__(256) void se_gate_kernel(
    const float* __restrict__ sumsq,
    const float* __restrict__ w_down, const float* __restrict__ b_down,
    const float* __restrict__ w_up, const float* __restrict__ b_up,
    float* __restrict__ gate)
{
    const int b = blockIdx.x;
    const int c = threadIdx.x;
    __shared__ float xs[CC];
    __shared__ float hs[INTERNAL];
    float g = sqrtf(sumsq[b * CC + c]);
    xs[c] = g / (g + 1e-6f);
    __syncthreads();
    if (c < INTERNAL) {
        float a = b_down[c];
        const float* wr = w_down + c * CC;
        for (int k = 0; k < CC; ++k) a += xs[k] * wr[k];
        hs[c] = fmaxf(a, 0.f);
    }
    __syncthreads();
    float a = b_up[c];
    const float* wu = w_up + c * INTERNAL;
    #pragma unroll
    for (int j = 0; j < INTERNAL; ++j) a += hs[j] * wu[j];
    gate[b * CC + c] = 1.f / (1.f + expf(-a));
}

__global__ __launch_bounds__(256) void se_scale_kernel(
    const float* __restrict__ in, const float* __restrict__ gate,
    float* __restrict__ out)
{
    const int bc = blockIdx.x;
    const float gv = gate[bc];
    const float4* pi = reinterpret_cast<const float4*>(in + (size_t)bc * HWSZ);
    float4* po = reinterpret_cast<float4*>(out + (size_t)bc * HWSZ);
    #pragma unroll 4
    for (int i = threadIdx.x; i < HW4; i += 256) {
        float4 v = pi[i];
        v.x *= gv; v.y *= gv; v.z *= gv; v.w *= gv;
        po[i] = v;
    }
}

extern "C" void kernel_launch(void* const* d_in, const int* in_sizes, int n_in,
                              void* d_out, int out_size, void* d_ws, size_t ws_size,
                              hipStream_t stream) {
    const float* inputs = (const float*)d_in[0];   // [B, C, H, W]
    const float* w_down = (const float*)d_in[1];   // [16, 256]
    const float* b_down = (const float*)d_in[2];   // [16]
    const float* w_up   = (const float*)d_in[3];   // [256, 16]
    const float* b_up   = (const float*)d_in[4];   // [256]
    float* out  = (float*)d_out;
    float* pbuf = (float*)d_ws;                    // BB*NBLK floats = 32 KB

    void* args[] = { (void*)&inputs, (void*)&out, (void*)&pbuf,
                     (void*)&w_down, (void*)&b_down, (void*)&w_up, (void*)&b_up };
    hipError_t err = hipLaunchCooperativeKernel(
        reinterpret_cast<void*>(se_fused_lds_kernel),
        dim3(NBLK), dim3(TPB), args, 0, stream);

    if (err != hipSuccess) {
        // deterministic fallback: proven 3-kernel path
        const int nbc = BB * CC;
        float* sumsq = pbuf;               // reuse ws
        float* gate  = sumsq + BB * CC;
        se_sumsq_kernel<<<nbc, 256, 0, stream>>>(inputs, sumsq);
        se_gate_kernel<<<BB, 256, 0, stream>>>(sumsq, w_down, b_down,
                                               w_up, b_up, gate);
        se_scale_kernel<<<nbc, 256, 0, stream>>>(inputs, gate, out);
    }
}

// Round 7
// 144.087 us; speedup vs baseline: 9.8710x; 9.8710x over previous
//
#include <hip/hip_runtime.h>
#include <math.h>

// Problem geometry (fixed by the reference)
#define BB 8
#define CC 256
#define HWSZ 36864            // floats per (b,c) slice
#define HW4 9216              // float4 per slice
#define TPB 256
#define IT 36                 // float4 per thread (36*256 = 9216)
#define INTERNAL 16
#define NSLICE (BB * CC)      // 2048

// clang ext-vector type: accepted by __builtin_nontemporal_{load,store}
typedef float f4 __attribute__((ext_vector_type(4)));

// ---- Pass 1: one block per (b,c) slice, full-slice sum of squares ----
// Normal (caching) loads: we WANT the input resident in L3 for pass 2.
__global__ __launch_bounds__(TPB) void se_sumsq_kernel(
    const float* __restrict__ in, float* __restrict__ sumsq)
{
    const int bc = blockIdx.x;
    const f4* p = reinterpret_cast<const f4*>(in + (size_t)bc * HWSZ);

    float a0 = 0.f, a1 = 0.f, a2 = 0.f, a3 = 0.f;
    #pragma unroll
    for (int i = 0; i < IT; i += 4) {
        f4 v0 = p[threadIdx.x + (i + 0) * TPB];
        f4 v1 = p[threadIdx.x + (i + 1) * TPB];
        f4 v2 = p[threadIdx.x + (i + 2) * TPB];
        f4 v3 = p[threadIdx.x + (i + 3) * TPB];
        a0 += v0.x * v0.x + v0.y * v0.y + v0.z * v0.z + v0.w * v0.w;
        a1 += v1.x * v1.x + v1.y * v1.y + v1.z * v1.z + v1.w * v1.w;
        a2 += v2.x * v2.x + v2.y * v2.y + v2.z * v2.z + v2.w * v2.w;
        a3 += v3.x * v3.x + v3.y * v3.y + v3.z * v3.z + v3.w * v3.w;
    }
    float acc = (a0 + a1) + (a2 + a3);
    for (int off = 32; off > 0; off >>= 1)
        acc += __shfl_down(acc, off, 64);

    __shared__ float red[4];
    const int lane = threadIdx.x & 63, wave = threadIdx.x >> 6;
    if (lane == 0) red[wave] = acc;
    __syncthreads();
    if (threadIdx.x == 0)
        sumsq[bc] = red[0] + red[1] + red[2] + red[3];
}

// ---- Pass 2: gate (in-block MLP) + scale, REVERSE slice order ----
// Reverse order = LIFO reuse of the input lines pass 1 left in L3.
// Non-temporal input loads (never read again) and non-temporal output
// stores (never read at all) avoid evicting the L3-resident input.
__global__ __launch_bounds__(TPB) void se_scale_kernel(
    const float* __restrict__ in,
    const float* __restrict__ sumsq,   // [B*C]
    const float* __restrict__ w_down,  // [16, 256]
    const float* __restrict__ b_down,  // [16]
    const float* __restrict__ w_up,    // [256, 16]
    const float* __restrict__ b_up,    // [256]
    float* __restrict__ out)
{
    const int s = (NSLICE - 1) - blockIdx.x;   // reverse order
    const int b = s >> 8;
    const int c = s & 255;
    const int tid = threadIdx.x;

    __shared__ float xs[CC];
    __shared__ float hs[INTERNAL];
    __shared__ float gsh;

    // x[k] for all channels of batch b
    {
        float g = sqrtf(sumsq[(b << 8) + tid]);
        xs[tid] = g / (g + 1e-6f);
    }
    __syncthreads();

    // h[j] = relu(b_down[j] + sum_k x[k]*w_down[j][k]); 16 threads per j
    {
        const int j = tid >> 4, l = tid & 15;
        const float* wr = w_down + j * CC;
        float a = 0.f;
        #pragma unroll
        for (int k = 0; k < CC / 16; ++k)
            a += xs[l + k * 16] * wr[l + k * 16];
        a += __shfl_down(a, 8, 16);
        a += __shfl_down(a, 4, 16);
        a += __shfl_down(a, 2, 16);
        a += __shfl_down(a, 1, 16);
        if (l == 0) hs[j] = fmaxf(a + b_down[j], 0.f);
    }
    __syncthreads();

    if (tid == 0) {
        float a = b_up[c];
        const float* wu = w_up + c * INTERNAL;
        #pragma unroll
        for (int j = 0; j < INTERNAL; ++j) a += hs[j] * wu[j];
        gsh = 1.f / (1.f + expf(-a));
    }
    __syncthreads();

    const float gv = gsh;
    const f4* pi = reinterpret_cast<const f4*>(in + (size_t)s * HWSZ);
    f4* po = reinterpret_cast<f4*>(out + (size_t)s * HWSZ);

    #pragma unroll
    for (int i = 0; i < IT; i += 4) {
        f4 v0 = __builtin_nontemporal_load(pi + tid + (i + 0) * TPB);
        f4 v1 = __builtin_nontemporal_load(pi + tid + (i + 1) * TPB);
        f4 v2 = __builtin_nontemporal_load(pi + tid + (i + 2) * TPB);
        f4 v3 = __builtin_nontemporal_load(pi + tid + (i + 3) * TPB);
        v0 *= gv; v1 *= gv; v2 *= gv; v3 *= gv;
        __builtin_nontemporal_store(v0, po + tid + (i + 0) * TPB);
        __builtin_nontemporal_store(v1, po + tid + (i + 1) * TPB);
        __builtin_nontemporal_store(v2, po + tid + (i + 2) * TPB);
        __builtin_nontemporal_store(v3, po + tid + (i + 3) * TPB);
    }
}

extern "C" void kernel_launch(void* const* d_in, const int* in_sizes, int n_in,
                              void* d_out, int out_size, void* d_ws, size_t ws_size,
                              hipStream_t stream) {
    const float* inputs = (const float*)d_in[0];   // [B, C, H, W]
    const float* w_down = (const float*)d_in[1];   // [16, 256]
    const float* b_down = (const float*)d_in[2];   // [16]
    const float* w_up   = (const float*)d_in[3];   // [256, 16]
    const float* b_up   = (const float*)d_in[4];   // [256]
    float* out   = (float*)d_out;
    float* sumsq = (float*)d_ws;                   // NSLICE floats = 8 KB

    se_sumsq_kernel<<<NSLICE, TPB, 0, stream>>>(inputs, sumsq);
    se_scale_kernel<<<NSLICE, TPB, 0, stream>>>(inputs, sumsq,
                                                w_down, b_down, w_up, b_up,
                                                out);
}